// Round 5
// baseline (137.753 us; speedup 1.0000x reference)
//
#include <hip/hip_runtime.h>
#include <math.h>

#define NT     128
#define NB     16
#define NH     512
#define SEQ_L  1024
#define FFT_N  2048
#define RS     0.70710678118654752f
#define C16    0.92387953251128675f   // cos(pi/8)
#define S16    0.38268343236508977f   // sin(pi/8)

// SoA LDS, pad every 16 floats: <=2-way bank aliasing on all access patterns.
#define P(x) ((x) + ((x) >> 4))
#define BUF_SZ 2176   // P(2047) = 2174

// K in stage-permuted order: 512 x 2048 complex = 8 MB BSS (graph-safe).
__device__ __align__(16) float2 g_kf[(size_t)NH * FFT_N];

__device__ __forceinline__ float2 cmul(float2 a, float2 b) {
    return make_float2(a.x * b.x - a.y * b.y, a.x * b.y + a.y * b.x);
}
__device__ __forceinline__ float2 cmulj(float2 a, float2 b) {  // a * conj(b)
    return make_float2(a.x * b.x + a.y * b.y, a.y * b.x - a.x * b.y);
}
__device__ __forceinline__ float2 cadd(float2 a, float2 b) { return make_float2(a.x + b.x, a.y + b.y); }
__device__ __forceinline__ float2 csub(float2 a, float2 b) { return make_float2(a.x - b.x, a.y - b.y); }

// In-place DFT4, natural order. SIGN=-1 fwd, SIGN=+1 = elementwise conjugate.
template <int SIGN>
__device__ __forceinline__ void dft4(float2 x[4]) {
    float2 s0 = cadd(x[0], x[2]), s1 = csub(x[0], x[2]);
    float2 s2 = cadd(x[1], x[3]), s3 = csub(x[1], x[3]);
    x[0] = cadd(s0, s2);
    x[2] = csub(s0, s2);
    if (SIGN < 0) {
        x[1] = make_float2(s1.x + s3.y, s1.y - s3.x);  // s1 - i*s3
        x[3] = make_float2(s1.x - s3.y, s1.y + s3.x);  // s1 + i*s3
    } else {
        x[1] = make_float2(s1.x - s3.y, s1.y + s3.x);
        x[3] = make_float2(s1.x + s3.y, s1.y - s3.x);
    }
}

// In-place DFT8, natural order (verified in R4).
template <int SIGN>
__device__ __forceinline__ void dft8(float2 x[8]) {
    float2 e0 = cadd(x[0], x[4]), e1 = cadd(x[1], x[5]);
    float2 e2 = cadd(x[2], x[6]), e3 = cadd(x[3], x[7]);
    float2 o0 = csub(x[0], x[4]), o1 = csub(x[1], x[5]);
    float2 o2 = csub(x[2], x[6]), o3 = csub(x[3], x[7]);
    float2 t1, t2, t3;
    if (SIGN < 0) {
        t1 = make_float2(RS * (o1.x + o1.y), RS * (o1.y - o1.x));
        t2 = make_float2(o2.y, -o2.x);
        t3 = make_float2(-RS * (o3.x - o3.y), -RS * (o3.x + o3.y));
    } else {
        t1 = make_float2(RS * (o1.x - o1.y), RS * (o1.x + o1.y));
        t2 = make_float2(-o2.y, o2.x);
        t3 = make_float2(RS * (-o3.x - o3.y), RS * (o3.x - o3.y));
    }
    float2 s0 = cadd(e0, e2), s1 = csub(e0, e2), s2 = cadd(e1, e3), s3 = csub(e1, e3);
    x[0] = cadd(s0, s2);
    x[4] = csub(s0, s2);
    float2 u0 = cadd(o0, t2), u1 = csub(o0, t2), u2 = cadd(t1, t3), u3 = csub(t1, t3);
    x[1] = cadd(u0, u2);
    x[5] = csub(u0, u2);
    if (SIGN < 0) {
        x[2] = make_float2(s1.x + s3.y, s1.y - s3.x);
        x[6] = make_float2(s1.x - s3.y, s1.y + s3.x);
        x[3] = make_float2(u1.x + u3.y, u1.y - u3.x);
        x[7] = make_float2(u1.x - u3.y, u1.y + u3.x);
    } else {
        x[2] = make_float2(s1.x - s3.y, s1.y + s3.x);
        x[6] = make_float2(s1.x + s3.y, s1.y - s3.x);
        x[3] = make_float2(u1.x - u3.y, u1.y + u3.x);
        x[7] = make_float2(u1.x + u3.y, u1.y - u3.x);
    }
}

// Internal W16 twiddles for the 4x4 CT decomposition of DFT16.
template <int SIGN>
__device__ __forceinline__ void dft16_twiddle(float2 v[4][4]) {
    const float sg = (SIGN < 0) ? -1.f : 1.f;
    const float2 W1 = make_float2(C16, sg * S16);
    const float2 W2 = make_float2(RS, sg * RS);
    const float2 W3 = make_float2(S16, sg * C16);
    const float2 W6 = make_float2(-RS, sg * RS);
    const float2 W9 = make_float2(-C16, -sg * S16);
    v[1][1] = cmul(v[1][1], W1);
    v[1][2] = cmul(v[1][2], W2);
    v[1][3] = cmul(v[1][3], W3);
    v[2][1] = cmul(v[2][1], W2);
    v[2][2] = make_float2(-sg * v[2][2].y, sg * v[2][2].x);  // *W16^4 = (0, sg)
    v[2][3] = cmul(v[2][3], W6);
    v[3][1] = cmul(v[3][1], W3);
    v[3][2] = cmul(v[3][2], W6);
    v[3][3] = cmul(v[3][3], W9);
}

// Full in-place DFT16, natural order: out[k] = sum_n in[n] W16^{SIGN*n*k}.
template <int SIGN>
__device__ __forceinline__ void dft16(float2 x[16]) {
    float2 v[4][4];
#pragma unroll
    for (int n0 = 0; n0 < 4; ++n0) {
        float2 a[4] = {x[n0], x[n0 + 4], x[n0 + 8], x[n0 + 12]};
        dft4<SIGN>(a);
        v[n0][0] = a[0]; v[n0][1] = a[1]; v[n0][2] = a[2]; v[n0][3] = a[3];
    }
    dft16_twiddle<SIGN>(v);
#pragma unroll
    for (int k0 = 0; k0 < 4; ++k0) {
        float2 a[4] = {v[0][k0], v[1][k0], v[2][k0], v[3][k0]};
        dft4<SIGN>(a);
        x[k0] = a[0]; x[k0 + 4] = a[1]; x[k0 + 8] = a[2]; x[k0 + 12] = a[3];
    }
}

// Forward DFT16 with inputs 8..15 implicitly zero (zero-padded conv input).
__device__ __forceinline__ void dft16_zero8(const float2 z[8], float2 x[16]) {
    float2 v[4][4];
#pragma unroll
    for (int n0 = 0; n0 < 4; ++n0) {
        float2 a = z[n0], b = z[n0 + 4];
        v[n0][0] = cadd(a, b);
        v[n0][1] = make_float2(a.x + b.y, a.y - b.x);   // a - i*b
        v[n0][2] = csub(a, b);
        v[n0][3] = make_float2(a.x - b.y, a.y + b.x);   // a + i*b
    }
    dft16_twiddle<-1>(v);
#pragma unroll
    for (int k0 = 0; k0 < 4; ++k0) {
        float2 a[4] = {v[0][k0], v[1][k0], v[2][k0], v[3][k0]};
        dft4<-1>(a);
        x[k0] = a[0]; x[k0 + 4] = a[1]; x[k0 + 8] = a[2]; x[k0 + 12] = a[3];
    }
}

// Inverse DFT16 computing only outputs 0..7 (adjoint of the zero-pad embed).
__device__ __forceinline__ void dft16_inv_low8(const float2 x[16], float2 y[8]) {
    float2 v[4][4];
#pragma unroll
    for (int n0 = 0; n0 < 4; ++n0) {
        float2 a[4] = {x[n0], x[n0 + 4], x[n0 + 8], x[n0 + 12]};
        dft4<+1>(a);
        v[n0][0] = a[0]; v[n0][1] = a[1]; v[n0][2] = a[2]; v[n0][3] = a[3];
    }
    dft16_twiddle<+1>(v);
#pragma unroll
    for (int k0 = 0; k0 < 4; ++k0) {
        float2 x0 = v[0][k0], x1 = v[1][k0], x2 = v[2][k0], x3 = v[3][k0];
        float2 s0 = cadd(x0, x2), s1 = csub(x0, x2);
        float2 s2 = cadd(x1, x3), s3 = csub(x1, x3);
        y[k0]     = cadd(s0, s2);                             // k1 = 0
        y[k0 + 4] = make_float2(s1.x - s3.y, s1.y + s3.x);    // k1 = 1: s1 + i*s3
    }
}

// ---- Kernel 1: K = fwd-chain(pad(k[h])) stored in stage-permuted order ----
__global__ __launch_bounds__(NT, 4) void kfft_kernel(const float* __restrict__ kin) {
    __shared__ float re[BUF_SZ];
    __shared__ float im[BUF_SZ];
    __shared__ float2 twlds[NT];
    const int t = threadIdx.x;
    const int h = blockIdx.x;
    float2 w1;
    {
        float sv, cv;
        sincosf(-6.283185307179586f * (float)t / (float)FFT_N, &sv, &cv);
        w1 = make_float2(cv, sv);
        twlds[t] = w1;
    }
    const float* krow = kin + (size_t)h * SEQ_L;
    // s1: dft16 over j of x[t+128j] (j>=8 zero), twiddle W2048^{t*c}
    {
        float2 z[8], x[16];
#pragma unroll
        for (int j = 0; j < 8; ++j) z[j] = make_float2(krow[t + 128 * j], 0.f);
        dft16_zero8(z, x);
        float2 w = w1;
#pragma unroll
        for (int c = 1; c < 16; ++c) { x[c] = cmul(x[c], w); w = cmul(w, w1); }
#pragma unroll
        for (int c = 0; c < 16; ++c) {
            const int id = P(t + 128 * c);
            re[id] = x[c].x; im[id] = x[c].y;
        }
    }
    __syncthreads();
    // s2: dft16 over j of {128c + r + 8j}, twiddle W128^{r*c2}, in-place
    const int cblk = t >> 3, r = t & 7;
    const int base = 128 * cblk + r;
    {
        float2 x[16];
#pragma unroll
        for (int j = 0; j < 16; ++j) {
            const int id = P(base + 8 * j);
            x[j] = make_float2(re[id], im[id]);
        }
        dft16<-1>(x);
        const float2 ws = twlds[16 * r];
        float2 w = ws;
#pragma unroll
        for (int c2 = 1; c2 < 16; ++c2) { x[c2] = cmul(x[c2], w); w = cmul(w, ws); }
#pragma unroll
        for (int c2 = 0; c2 < 16; ++c2) {
            const int id = P(base + 8 * c2);
            re[id] = x[c2].x; im[id] = x[c2].y;
        }
    }
    __syncthreads();
    // s3: twiddle-free dft8 on consecutive groups of 8, store to g_kf
#pragma unroll
    for (int gi = 0; gi < 2; ++gi) {
        const int g = 2 * t + gi;
        float2 x[8];
#pragma unroll
        for (int l = 0; l < 8; ++l) {
            const int id = P(8 * g + l);
            x[l] = make_float2(re[id], im[id]);
        }
        dft8<-1>(x);
        float4* o4 = (float4*)(g_kf + (size_t)h * FFT_N + 8 * g);
#pragma unroll
        for (int l = 0; l < 4; ++l)
            o4[l] = make_float4(x[2 * l].x, x[2 * l].y, x[2 * l + 1].x, x[2 * l + 1].y);
    }
}

// ---- Kernel 2: rows (2bp,h),(2bp+1,h) packed: fwd chain -> *K -> adjoint ----
__global__ __launch_bounds__(NT, 4) void conv_pair_kernel(const float* __restrict__ u,
                                                          const float* __restrict__ D,
                                                          float* __restrict__ out) {
    __shared__ float re[BUF_SZ];
    __shared__ float im[BUF_SZ];
    __shared__ float2 twlds[NT];
    const int t = threadIdx.x;
    const int h = blockIdx.x & (NH - 1);
    const int bp = blockIdx.x >> 9;
    const size_t row0 = (size_t)(2 * bp) * NH + h;
    const size_t row1 = row0 + NH;
    float2 w1;
    {
        float sv, cv;
        sincosf(-6.283185307179586f * (float)t / (float)FFT_N, &sv, &cv);
        w1 = make_float2(cv, sv);
        twlds[t] = w1;
    }
    const float* u0 = u + row0 * SEQ_L;
    const float* u1 = u + row1 * SEQ_L;
    float ur0[8], ur1[8];
#pragma unroll
    for (int j = 0; j < 8; ++j) {
        ur0[j] = u0[t + 128 * j];
        ur1[j] = u1[t + 128 * j];
    }
    // s1 fwd (write-only into LDS)
    {
        float2 z[8], x[16];
#pragma unroll
        for (int j = 0; j < 8; ++j) z[j] = make_float2(ur0[j], ur1[j]);
        dft16_zero8(z, x);
        float2 w = w1;
#pragma unroll
        for (int c = 1; c < 16; ++c) { x[c] = cmul(x[c], w); w = cmul(w, w1); }
#pragma unroll
        for (int c = 0; c < 16; ++c) {
            const int id = P(t + 128 * c);
            re[id] = x[c].x; im[id] = x[c].y;
        }
    }
    __syncthreads();
    // s2 fwd (in-place)
    const int cblk = t >> 3, r = t & 7;
    const int base = 128 * cblk + r;
    const float2 ws = twlds[16 * r];   // W_128^r
    {
        float2 x[16];
#pragma unroll
        for (int j = 0; j < 16; ++j) {
            const int id = P(base + 8 * j);
            x[j] = make_float2(re[id], im[id]);
        }
        dft16<-1>(x);
        float2 w = ws;
#pragma unroll
        for (int c2 = 1; c2 < 16; ++c2) { x[c2] = cmul(x[c2], w); w = cmul(w, ws); }
#pragma unroll
        for (int c2 = 0; c2 < 16; ++c2) {
            const int id = P(base + 8 * c2);
            re[id] = x[c2].x; im[id] = x[c2].y;
        }
    }
    __syncthreads();
    // mid: dft8 fwd + elementwise *K + dft8 inv, all in registers
    {
        const float2* kfr = g_kf + (size_t)h * FFT_N;
#pragma unroll
        for (int gi = 0; gi < 2; ++gi) {
            const int g = 2 * t + gi;
            float2 x[8];
#pragma unroll
            for (int l = 0; l < 8; ++l) {
                const int id = P(8 * g + l);
                x[l] = make_float2(re[id], im[id]);
            }
            dft8<-1>(x);
            const float4* k4 = (const float4*)(kfr + 8 * g);
#pragma unroll
            for (int l = 0; l < 4; ++l) {
                float4 kk = k4[l];
                x[2 * l]     = cmul(x[2 * l],     make_float2(kk.x, kk.y));
                x[2 * l + 1] = cmul(x[2 * l + 1], make_float2(kk.z, kk.w));
            }
            dft8<+1>(x);
#pragma unroll
            for (int l = 0; l < 8; ++l) {
                const int id = P(8 * g + l);
                re[id] = x[l].x; im[id] = x[l].y;
            }
        }
    }
    __syncthreads();
    // inv s2 (adjoint: conj twiddle, then inverse butterfly; in-place)
    {
        float2 x[16];
#pragma unroll
        for (int c2 = 0; c2 < 16; ++c2) {
            const int id = P(base + 8 * c2);
            x[c2] = make_float2(re[id], im[id]);
        }
        float2 w = ws;
#pragma unroll
        for (int c2 = 1; c2 < 16; ++c2) { x[c2] = cmulj(x[c2], w); w = cmul(w, ws); }
        dft16<+1>(x);
#pragma unroll
        for (int j = 0; j < 16; ++j) {
            const int id = P(base + 8 * j);
            re[id] = x[j].x; im[id] = x[j].y;
        }
    }
    __syncthreads();
    // inv s1 + epilogue (only low 8 outputs needed)
    {
        float2 x[16];
#pragma unroll
        for (int c = 0; c < 16; ++c) {
            const int id = P(t + 128 * c);
            x[c] = make_float2(re[id], im[id]);
        }
        float2 w = w1;
#pragma unroll
        for (int c = 1; c < 16; ++c) { x[c] = cmulj(x[c], w); w = cmul(w, w1); }
        float2 y[8];
        dft16_inv_low8(x, y);
        const float Dh = D[h];
        const float invN = 1.0f / (float)FFT_N;
        float* o0row = out + row0 * SEQ_L;
        float* o1row = out + row1 * SEQ_L;
#pragma unroll
        for (int j = 0; j < 8; ++j) {
            o0row[t + 128 * j] = y[j].x * invN + ur0[j] * Dh;
            o1row[t + 128 * j] = y[j].y * invN + ur1[j] * Dh;
        }
    }
}

extern "C" void kernel_launch(void* const* d_in, const int* in_sizes, int n_in,
                              void* d_out, int out_size, void* d_ws, size_t ws_size,
                              hipStream_t stream) {
    const float* u = (const float*)d_in[0];
    const float* k = (const float*)d_in[1];
    const float* D = (const float*)d_in[2];
    float* out = (float*)d_out;

    kfft_kernel<<<NH, NT, 0, stream>>>(k);
    conv_pair_kernel<<<NB * NH / 2, NT, 0, stream>>>(u, D, out);
}

// Round 6
// 113.437 us; speedup vs baseline: 1.2144x; 1.2144x over previous
//
#include <hip/hip_runtime.h>
#include <math.h>

#define NT     128
#define NB     16
#define NH     512
#define SEQ_L  1024
#define FFT_N  2048
#define RS     0.70710678118654752f
#define C16    0.92387953251128675f   // cos(pi/8)
#define S16    0.38268343236508977f   // sin(pi/8)

// SoA LDS, pad every 16 floats: <=2-way bank aliasing on all access patterns.
#define P(x) ((x) + ((x) >> 4))
#define BUF_SZ 2176   // P(2047) = 2174

// K in stage-permuted order: 512 x 2048 complex = 8 MB BSS (graph-safe).
__device__ __align__(16) float2 g_kf[(size_t)NH * FFT_N];

__device__ __forceinline__ float2 cmul(float2 a, float2 b) {
    return make_float2(a.x * b.x - a.y * b.y, a.x * b.y + a.y * b.x);
}
__device__ __forceinline__ float2 cmulj(float2 a, float2 b) {  // a * conj(b)
    return make_float2(a.x * b.x + a.y * b.y, a.y * b.x - a.x * b.y);
}
__device__ __forceinline__ float2 cadd(float2 a, float2 b) { return make_float2(a.x + b.x, a.y + b.y); }
__device__ __forceinline__ float2 csub(float2 a, float2 b) { return make_float2(a.x - b.x, a.y - b.y); }

// In-place DFT4, natural order. SIGN=-1 fwd, SIGN=+1 inverse.
template <int SIGN>
__device__ __forceinline__ void dft4(float2 x[4]) {
    float2 s0 = cadd(x[0], x[2]), s1 = csub(x[0], x[2]);
    float2 s2 = cadd(x[1], x[3]), s3 = csub(x[1], x[3]);
    x[0] = cadd(s0, s2);
    x[2] = csub(s0, s2);
    if (SIGN < 0) {
        x[1] = make_float2(s1.x + s3.y, s1.y - s3.x);  // s1 - i*s3
        x[3] = make_float2(s1.x - s3.y, s1.y + s3.x);  // s1 + i*s3
    } else {
        x[1] = make_float2(s1.x - s3.y, s1.y + s3.x);
        x[3] = make_float2(s1.x + s3.y, s1.y - s3.x);
    }
}

// In-place DFT8, natural order (verified R4/R5).
template <int SIGN>
__device__ __forceinline__ void dft8(float2 x[8]) {
    float2 e0 = cadd(x[0], x[4]), e1 = cadd(x[1], x[5]);
    float2 e2 = cadd(x[2], x[6]), e3 = cadd(x[3], x[7]);
    float2 o0 = csub(x[0], x[4]), o1 = csub(x[1], x[5]);
    float2 o2 = csub(x[2], x[6]), o3 = csub(x[3], x[7]);
    float2 t1, t2, t3;
    if (SIGN < 0) {
        t1 = make_float2(RS * (o1.x + o1.y), RS * (o1.y - o1.x));
        t2 = make_float2(o2.y, -o2.x);
        t3 = make_float2(-RS * (o3.x - o3.y), -RS * (o3.x + o3.y));
    } else {
        t1 = make_float2(RS * (o1.x - o1.y), RS * (o1.x + o1.y));
        t2 = make_float2(-o2.y, o2.x);
        t3 = make_float2(RS * (-o3.x - o3.y), RS * (o3.x - o3.y));
    }
    float2 s0 = cadd(e0, e2), s1 = csub(e0, e2), s2 = cadd(e1, e3), s3 = csub(e1, e3);
    x[0] = cadd(s0, s2);
    x[4] = csub(s0, s2);
    float2 u0 = cadd(o0, t2), u1 = csub(o0, t2), u2 = cadd(t1, t3), u3 = csub(t1, t3);
    x[1] = cadd(u0, u2);
    x[5] = csub(u0, u2);
    if (SIGN < 0) {
        x[2] = make_float2(s1.x + s3.y, s1.y - s3.x);
        x[6] = make_float2(s1.x - s3.y, s1.y + s3.x);
        x[3] = make_float2(u1.x + u3.y, u1.y - u3.x);
        x[7] = make_float2(u1.x - u3.y, u1.y + u3.x);
    } else {
        x[2] = make_float2(s1.x - s3.y, s1.y + s3.x);
        x[6] = make_float2(s1.x + s3.y, s1.y - s3.x);
        x[3] = make_float2(u1.x - u3.y, u1.y + u3.x);
        x[7] = make_float2(u1.x + u3.y, u1.y - u3.x);
    }
}

// Internal W16 twiddles for the 4x4 CT decomposition of DFT16.
template <int SIGN>
__device__ __forceinline__ void dft16_twiddle(float2 v[4][4]) {
    const float sg = (SIGN < 0) ? -1.f : 1.f;
    const float2 W1 = make_float2(C16, sg * S16);
    const float2 W2 = make_float2(RS, sg * RS);
    const float2 W3 = make_float2(S16, sg * C16);
    const float2 W6 = make_float2(-RS, sg * RS);
    const float2 W9 = make_float2(-C16, -sg * S16);
    v[1][1] = cmul(v[1][1], W1);
    v[1][2] = cmul(v[1][2], W2);
    v[1][3] = cmul(v[1][3], W3);
    v[2][1] = cmul(v[2][1], W2);
    v[2][2] = make_float2(-sg * v[2][2].y, sg * v[2][2].x);  // *W16^4
    v[2][3] = cmul(v[2][3], W6);
    v[3][1] = cmul(v[3][1], W3);
    v[3][2] = cmul(v[3][2], W6);
    v[3][3] = cmul(v[3][3], W9);
}

// Full in-place DFT16, natural order.
template <int SIGN>
__device__ __forceinline__ void dft16(float2 x[16]) {
    float2 v[4][4];
#pragma unroll
    for (int n0 = 0; n0 < 4; ++n0) {
        float2 a[4] = {x[n0], x[n0 + 4], x[n0 + 8], x[n0 + 12]};
        dft4<SIGN>(a);
        v[n0][0] = a[0]; v[n0][1] = a[1]; v[n0][2] = a[2]; v[n0][3] = a[3];
    }
    dft16_twiddle<SIGN>(v);
#pragma unroll
    for (int k0 = 0; k0 < 4; ++k0) {
        float2 a[4] = {v[0][k0], v[1][k0], v[2][k0], v[3][k0]};
        dft4<SIGN>(a);
        x[k0] = a[0]; x[k0 + 4] = a[1]; x[k0 + 8] = a[2]; x[k0 + 12] = a[3];
    }
}

// Forward DFT16 with inputs 8..15 implicitly zero.
__device__ __forceinline__ void dft16_zero8(const float2 z[8], float2 x[16]) {
    float2 v[4][4];
#pragma unroll
    for (int n0 = 0; n0 < 4; ++n0) {
        float2 a = z[n0], b = z[n0 + 4];
        v[n0][0] = cadd(a, b);
        v[n0][1] = make_float2(a.x + b.y, a.y - b.x);   // a - i*b
        v[n0][2] = csub(a, b);
        v[n0][3] = make_float2(a.x - b.y, a.y + b.x);   // a + i*b
    }
    dft16_twiddle<-1>(v);
#pragma unroll
    for (int k0 = 0; k0 < 4; ++k0) {
        float2 a[4] = {v[0][k0], v[1][k0], v[2][k0], v[3][k0]};
        dft4<-1>(a);
        x[k0] = a[0]; x[k0 + 4] = a[1]; x[k0 + 8] = a[2]; x[k0 + 12] = a[3];
    }
}

// Inverse DFT16 computing only outputs 0..7.
__device__ __forceinline__ void dft16_inv_low8(const float2 x[16], float2 y[8]) {
    float2 v[4][4];
#pragma unroll
    for (int n0 = 0; n0 < 4; ++n0) {
        float2 a[4] = {x[n0], x[n0 + 4], x[n0 + 8], x[n0 + 12]};
        dft4<+1>(a);
        v[n0][0] = a[0]; v[n0][1] = a[1]; v[n0][2] = a[2]; v[n0][3] = a[3];
    }
    dft16_twiddle<+1>(v);
#pragma unroll
    for (int k0 = 0; k0 < 4; ++k0) {
        float2 x0 = v[0][k0], x1 = v[1][k0], x2 = v[2][k0], x3 = v[3][k0];
        float2 s0 = cadd(x0, x2), s1 = csub(x0, x2);
        float2 s2 = cadd(x1, x3), s3 = csub(x1, x3);
        y[k0]     = cadd(s0, s2);                             // k1 = 0
        y[k0 + 4] = make_float2(s1.x - s3.y, s1.y + s3.x);    // k1 = 1
    }
}

// ---- Kernel 1: K = fwd-chain(pad(k[h])) stored in stage-permuted order ----
__global__ __launch_bounds__(NT, 2) void kfft_kernel(const float* __restrict__ kin) {
    __shared__ float re[BUF_SZ];
    __shared__ float im[BUF_SZ];
    __shared__ float2 twlds[NT];
    const int t = threadIdx.x;
    const int h = blockIdx.x;
    float2 w1;
    {
        float sv, cv;
        sincosf(-6.283185307179586f * (float)t / (float)FFT_N, &sv, &cv);
        w1 = make_float2(cv, sv);
        twlds[t] = w1;
    }
    const float* krow = kin + (size_t)h * SEQ_L;
    {
        float2 z[8], x[16];
#pragma unroll
        for (int j = 0; j < 8; ++j) z[j] = make_float2(krow[t + 128 * j], 0.f);
        dft16_zero8(z, x);
        float2 w = w1;
#pragma unroll
        for (int c = 1; c < 16; ++c) { x[c] = cmul(x[c], w); w = cmul(w, w1); }
#pragma unroll
        for (int c = 0; c < 16; ++c) {
            const int id = P(t + 128 * c);
            re[id] = x[c].x; im[id] = x[c].y;
        }
    }
    __syncthreads();
    const int cblk = t >> 3, r = t & 7;
    const int base = 128 * cblk + r;
    {
        float2 x[16];
#pragma unroll
        for (int j = 0; j < 16; ++j) {
            const int id = P(base + 8 * j);
            x[j] = make_float2(re[id], im[id]);
        }
        dft16<-1>(x);
        const float2 ws = twlds[16 * r];
        float2 w = ws;
#pragma unroll
        for (int c2 = 1; c2 < 16; ++c2) { x[c2] = cmul(x[c2], w); w = cmul(w, ws); }
#pragma unroll
        for (int c2 = 0; c2 < 16; ++c2) {
            const int id = P(base + 8 * c2);
            re[id] = x[c2].x; im[id] = x[c2].y;
        }
    }
    __syncthreads();
#pragma unroll
    for (int gi = 0; gi < 2; ++gi) {
        const int g = 2 * t + gi;
        float2 x[8];
#pragma unroll
        for (int l = 0; l < 8; ++l) {
            const int id = P(8 * g + l);
            x[l] = make_float2(re[id], im[id]);
        }
        dft8<-1>(x);
        float4* o4 = (float4*)(g_kf + (size_t)h * FFT_N + 8 * g);
#pragma unroll
        for (int l = 0; l < 4; ++l)
            o4[l] = make_float4(x[2 * l].x, x[2 * l].y, x[2 * l + 1].x, x[2 * l + 1].y);
    }
}

// ---- Kernel 2: rows (2bp,h),(2bp+1,h) packed: fwd chain -> *K -> adjoint ----
__global__ __launch_bounds__(NT, 2) void conv_pair_kernel(const float* __restrict__ u,
                                                          const float* __restrict__ D,
                                                          float* __restrict__ out) {
    __shared__ float re[BUF_SZ];
    __shared__ float im[BUF_SZ];
    __shared__ float2 twlds[NT];
    const int t = threadIdx.x;
    const int h = blockIdx.x & (NH - 1);
    const int bp = blockIdx.x >> 9;
    const size_t row0 = (size_t)(2 * bp) * NH + h;
    const size_t row1 = row0 + NH;
    float2 w1;
    {
        float sv, cv;
        sincosf(-6.283185307179586f * (float)t / (float)FFT_N, &sv, &cv);
        w1 = make_float2(cv, sv);
        twlds[t] = w1;
    }
    const float* u0 = u + row0 * SEQ_L;
    const float* u1 = u + row1 * SEQ_L;
    // s1 fwd (write-only into LDS); u loaded fresh, NOT kept live (VGPR pressure)
    {
        float2 z[8], x[16];
#pragma unroll
        for (int j = 0; j < 8; ++j)
            z[j] = make_float2(u0[t + 128 * j], u1[t + 128 * j]);
        dft16_zero8(z, x);
        float2 w = w1;
#pragma unroll
        for (int c = 1; c < 16; ++c) { x[c] = cmul(x[c], w); w = cmul(w, w1); }
#pragma unroll
        for (int c = 0; c < 16; ++c) {
            const int id = P(t + 128 * c);
            re[id] = x[c].x; im[id] = x[c].y;
        }
    }
    __syncthreads();
    // s2 fwd (in-place)
    const int cblk = t >> 3, r = t & 7;
    const int base = 128 * cblk + r;
    const float2 ws = twlds[16 * r];   // W_128^r
    {
        float2 x[16];
#pragma unroll
        for (int j = 0; j < 16; ++j) {
            const int id = P(base + 8 * j);
            x[j] = make_float2(re[id], im[id]);
        }
        dft16<-1>(x);
        float2 w = ws;
#pragma unroll
        for (int c2 = 1; c2 < 16; ++c2) { x[c2] = cmul(x[c2], w); w = cmul(w, ws); }
#pragma unroll
        for (int c2 = 0; c2 < 16; ++c2) {
            const int id = P(base + 8 * c2);
            re[id] = x[c2].x; im[id] = x[c2].y;
        }
    }
    __syncthreads();
    // mid: dft8 fwd + elementwise *K + dft8 inv, all in registers
    {
        const float2* kfr = g_kf + (size_t)h * FFT_N;
#pragma unroll
        for (int gi = 0; gi < 2; ++gi) {
            const int g = 2 * t + gi;
            float2 x[8];
#pragma unroll
            for (int l = 0; l < 8; ++l) {
                const int id = P(8 * g + l);
                x[l] = make_float2(re[id], im[id]);
            }
            dft8<-1>(x);
            const float4* k4 = (const float4*)(kfr + 8 * g);
#pragma unroll
            for (int l = 0; l < 4; ++l) {
                float4 kk = k4[l];
                x[2 * l]     = cmul(x[2 * l],     make_float2(kk.x, kk.y));
                x[2 * l + 1] = cmul(x[2 * l + 1], make_float2(kk.z, kk.w));
            }
            dft8<+1>(x);
#pragma unroll
            for (int l = 0; l < 8; ++l) {
                const int id = P(8 * g + l);
                re[id] = x[l].x; im[id] = x[l].y;
            }
        }
    }
    __syncthreads();
    // inv s2 (adjoint: conj twiddle, then inverse butterfly; in-place)
    {
        float2 x[16];
#pragma unroll
        for (int c2 = 0; c2 < 16; ++c2) {
            const int id = P(base + 8 * c2);
            x[c2] = make_float2(re[id], im[id]);
        }
        float2 w = ws;
#pragma unroll
        for (int c2 = 1; c2 < 16; ++c2) { x[c2] = cmulj(x[c2], w); w = cmul(w, ws); }
        dft16<+1>(x);
#pragma unroll
        for (int j = 0; j < 16; ++j) {
            const int id = P(base + 8 * j);
            re[id] = x[j].x; im[id] = x[j].y;
        }
    }
    __syncthreads();
    // inv s1 + epilogue (only low 8 outputs needed); u re-loaded (L2/L3 hot)
    {
        float2 x[16];
#pragma unroll
        for (int c = 0; c < 16; ++c) {
            const int id = P(t + 128 * c);
            x[c] = make_float2(re[id], im[id]);
        }
        float2 w = w1;
#pragma unroll
        for (int c = 1; c < 16; ++c) { x[c] = cmulj(x[c], w); w = cmul(w, w1); }
        float2 y[8];
        dft16_inv_low8(x, y);
        const float Dh = D[h];
        const float invN = 1.0f / (float)FFT_N;
        float* o0row = out + row0 * SEQ_L;
        float* o1row = out + row1 * SEQ_L;
#pragma unroll
        for (int j = 0; j < 8; ++j) {
            o0row[t + 128 * j] = y[j].x * invN + u0[t + 128 * j] * Dh;
            o1row[t + 128 * j] = y[j].y * invN + u1[t + 128 * j] * Dh;
        }
    }
}

extern "C" void kernel_launch(void* const* d_in, const int* in_sizes, int n_in,
                              void* d_out, int out_size, void* d_ws, size_t ws_size,
                              hipStream_t stream) {
    const float* u = (const float*)d_in[0];
    const float* k = (const float*)d_in[1];
    const float* D = (const float*)d_in[2];
    float* out = (float*)d_out;

    kfft_kernel<<<NH, NT, 0, stream>>>(k);
    conv_pair_kernel<<<NB * NH / 2, NT, 0, stream>>>(u, D, out);
}